// Round 5
// baseline (11104.122 us; speedup 1.0000x reference)
//
#include <hip/hip_runtime.h>
#include <hip/hip_cooperative_groups.h>

namespace cg = cooperative_groups;

typedef _Float16 f16;
typedef _Float16 half8 __attribute__((ext_vector_type(8)));
typedef float float4v __attribute__((ext_vector_type(4)));

constexpr int kB  = 512;   // batch
constexpr int kT  = 512;   // seq len
constexpr int kI  = 128;   // input dim
constexpr int kH  = 512;   // hidden
constexpr int kNG = 2048;  // 4*H
constexpr int kO  = 128;   // output dim

// Padded K-stride (f16) for resident W in LDS. Byte stride 1300 -> 16B-group
// bank start = (5*lc + 4*lj) % 32, distinct for lc=0..15 => conflict-free b128.
constexpr int LDK = 650;

__device__ __forceinline__ float fsig(float v)  { return 1.0f / (1.0f + __expf(-v)); }
__device__ __forceinline__ float ftanh(float v) { return 1.0f - 2.0f / (1.0f + __expf(2.0f * v)); }

// 256 WGs x 256 threads (1 WG/CU, cooperative for co-residency + 2 one-time grid syncs).
// WG: bg = blockIdx&7 (64 batch rows), ng = blockIdx>>3 (h-slice of 16 cols).
//   bg=&7 co-locates each 32-WG group on one XCD under round-robin dispatch
//   (performance only; AGENT-scope fences keep correctness under any mapping).
// Per-step sync: 32-WG group barrier with RELAXED polls + one release/acquire
// fence pair per WG per step (R4's per-poll ACQUIRE = L2-inv storm, 15us/step).
__global__ __launch_bounds__(256, 1) void lstm_fused(
    const float* __restrict__ x,  const float* __restrict__ Wx,
    const float* __restrict__ Wh, const float* __restrict__ bias,
    const float* __restrict__ Wp, const float* __restrict__ bp,
    float* __restrict__ out, float* __restrict__ ws)
{
  cg::grid_group grid = cg::this_grid();

  // Resident weight slice, fp16: [col 0..63][k 0..639], padded stride LDK.
  // col c -> global gate col (c>>4)*512 + ng*16 + (c&15); k<512 -> Wh[k], else Wx[k-512]
  __shared__ __align__(16) f16 w_lds[64 * LDK];   // 83,200 B

  const int tid = threadIdx.x;
  const int wg  = blockIdx.x;
  const int bg  = wg & 7;
  const int ng  = wg >> 3;
  const int b0  = bg * 64;
  const int wv  = tid >> 6;     // wave 0..3
  const int l   = tid & 63;
  const int lc  = l & 15;       // fragment row/col
  const int lj  = l >> 4;       // k-group 0..3

  f16* h16a = (f16*)ws;                 // [512][512] fp16
  f16* h16b = h16a + kB * kH;
  unsigned* bar = (unsigned*)(h16b + kB * kH);  // 8 groups x 64 uints: cnt @+0, gen @+32 (128B apart)

  // ---- init: zero h0 and barrier area (ws poisoned; re-init every call) ----
  {
    int gtid = wg * 256 + tid;                 // 65536 threads
    unsigned* p = (unsigned*)h16a;             // 131072 u32 = 512 KB
    p[gtid * 2] = 0u; p[gtid * 2 + 1] = 0u;
    if (gtid < 512) bar[gtid] = 0u;
  }

  // ---- one-time: stage W slice -> LDS fp16 ----
  for (int idx = tid; idx < 64 * 640; idx += 256) {
    int c = idx & 63;
    int k = idx >> 6;
    int gcol = (c >> 4) * 512 + ng * 16 + (c & 15);
    float v = (k < 512) ? Wh[(long)k * kNG + gcol]
                        : Wx[(long)(k - 512) * kNG + gcol];
    w_lds[c * LDK + k] = (f16)v;
  }
  float bb[4];
  #pragma unroll
  for (int g = 0; g < 4; ++g) bb[g] = bias[g * 512 + ng * 16 + lc];

  float ce[4] = {0.f, 0.f, 0.f, 0.f};
  const int arow = b0 + wv * 16 + lc;
  const f16* wbase = w_lds + lc * LDK + lj * 8;
  const float* xrow = x + (long)arow * (kT * kI) + lj * 8;

  grid.sync();   // h zeroed, bar zeroed, w_lds staged, everyone resident

  unsigned* bcnt = bar + bg * 64;
  unsigned* bgen = bar + bg * 64 + 32;

  // preload x for t=0 (subsequent steps prefetched before the barrier)
  float4v xa[4], xb[4];
  #pragma unroll
  for (int q = 0; q < 4; ++q) {
    xa[q] = *(const float4v*)(xrow + q * 32);
    xb[q] = *(const float4v*)(xrow + q * 32 + 4);
  }

  for (int t = 0; t < kT; ++t) {
    const f16* hc = (t & 1) ? h16b : h16a;
    f16*       hn = (t & 1) ? h16a : h16b;

    const f16* hp = hc + (long)arow * kH + lj * 8;

    half8 ah[16];
    #pragma unroll
    for (int p = 0; p < 16; ++p) ah[p] = *(const half8*)(hp + p * 32);

    float4v acc[4];
    #pragma unroll
    for (int g = 0; g < 4; ++g) acc[g] = float4v{bb[g], bb[g], bb[g], bb[g]};

    // h @ Wh : 16 k-steps of 32, B from LDS (conflict-free layout)
    #pragma unroll
    for (int ks = 0; ks < 16; ++ks) {
      #pragma unroll
      for (int g = 0; g < 4; ++g) {
        half8 bf = *(const half8*)(wbase + g * 16 * LDK + ks * 32);
        acc[g] = __builtin_amdgcn_mfma_f32_16x16x32_f16(ah[ks], bf, acc[g], 0, 0, 0);
      }
    }
    // x_t @ Wx : 4 k-steps
    #pragma unroll
    for (int q = 0; q < 4; ++q) {
      half8 a;
      #pragma unroll
      for (int e = 0; e < 4; ++e) { a[e] = (f16)xa[q][e]; a[e + 4] = (f16)xb[q][e]; }
      #pragma unroll
      for (int g = 0; g < 4; ++g) {
        half8 bf = *(const half8*)(wbase + g * 16 * LDK + 512 + q * 32);
        acc[g] = __builtin_amdgcn_mfma_f32_16x16x32_f16(a, bf, acc[g], 0, 0, 0);
      }
    }

    // prefetch x for t+1 (read-only; overlaps gate update + barrier)
    if (t + 1 < kT) {
      const float* xn = xrow + (long)(t + 1) * kI;
      #pragma unroll
      for (int q = 0; q < 4; ++q) {
        xa[q] = *(const float4v*)(xn + q * 32);
        xb[q] = *(const float4v*)(xn + q * 32 + 4);
      }
    }

    // gate update in registers; c never leaves VGPRs
    #pragma unroll
    for (int e = 0; e < 4; ++e) {
      float gv = ftanh(acc[0][e]);
      float iv = fsig(acc[1][e]);
      float fv = fsig(acc[2][e]);
      float ov = fsig(acc[3][e]);
      float cn = gv * iv + ce[e] * fv;
      ce[e] = cn;
      hn[(long)(b0 + wv * 16 + lj * 4 + e) * kH + ng * 16 + lc] = (f16)(ftanh(cn) * ov);
    }

    // ---- 32-WG group barrier, cheap form ----
    // __syncthreads drains all waves' h stores (vmcnt) to L2. One RELEASE
    // fence per WG writes dirty L2 back (cross-XCD visible), then RELAXED
    // arrival/publish/poll (no per-poll cache maintenance). After the
    // closing __syncthreads, one ACQUIRE fence invalidates stale L1/L2
    // before next step's h reads.
    __syncthreads();
    if (tid == 0) {
      __builtin_amdgcn_fence(__ATOMIC_RELEASE, "agent");
      unsigned old = __hip_atomic_fetch_add(bcnt, 1u, __ATOMIC_RELAXED, __HIP_MEMORY_SCOPE_AGENT);
      if (old == (unsigned)(t * 32 + 31)) {
        __hip_atomic_store(bgen, (unsigned)(t + 1), __ATOMIC_RELAXED, __HIP_MEMORY_SCOPE_AGENT);
      } else {
        while (__hip_atomic_load(bgen, __ATOMIC_RELAXED, __HIP_MEMORY_SCOPE_AGENT) < (unsigned)(t + 1)) {
          __builtin_amdgcn_s_sleep(1);
        }
      }
    }
    __syncthreads();
    __builtin_amdgcn_fence(__ATOMIC_ACQUIRE, "agent");
  }

  grid.sync();   // all bg-groups done before cross-group projection reads

  // ---- projection + softmax: rows wg*2, wg*2+1 (final h in h16a) ----
  const f16* hf = h16a;
  float* hrow = (float*)w_lds;             // reuse LDS
  float* red  = (float*)w_lds + 2 * kH;
  for (int i = tid; i < 2 * kH; i += 256) {
    int r = i >> 9, k = i & 511;
    hrow[i] = (float)hf[(long)(wg * 2 + r) * kH + k];
  }
  __syncthreads();

  const int orow = tid >> 7;   // 0..1
  const int oc   = tid & 127;  // 0..127
  float p = bp[oc];
  #pragma unroll 8
  for (int k = 0; k < kH; ++k)
    p += hrow[orow * kH + k] * Wp[(long)k * kO + oc];

  red[tid] = p;
  __syncthreads();
  float m = -1e30f;
  for (int j = 0; j < 128; ++j) m = fmaxf(m, red[orow * 128 + j]);
  __syncthreads();
  float e = __expf(p - m);
  red[tid] = e;
  __syncthreads();
  float s = 0.f;
  for (int j = 0; j < 128; ++j) s += red[orow * 128 + j];
  out[(long)(wg * 2 + orow) * kO + oc] = e / s;
}

extern "C" void kernel_launch(void* const* d_in, const int* in_sizes, int n_in,
                              void* d_out, int out_size, void* d_ws, size_t ws_size,
                              hipStream_t stream) {
  const float* x  = (const float*)d_in[0];
  const float* Wx = (const float*)d_in[1];
  const float* Wh = (const float*)d_in[2];
  const float* b  = (const float*)d_in[3];
  const float* Wp = (const float*)d_in[4];
  const float* bp = (const float*)d_in[5];
  float* out = (float*)d_out;
  float* ws  = (float*)d_ws;

  void* args[] = { &x, &Wx, &Wh, &b, &Wp, &bp, &out, &ws };
  hipLaunchCooperativeKernel((void*)lstm_fused, dim3(256), dim3(256), args, 0, stream);
}

// Round 6
// 5815.705 us; speedup vs baseline: 1.9093x; 1.9093x over previous
//
#include <hip/hip_runtime.h>
#include <hip/hip_cooperative_groups.h>

namespace cg = cooperative_groups;

typedef _Float16 f16;
typedef _Float16 half8 __attribute__((ext_vector_type(8)));
typedef float float4v __attribute__((ext_vector_type(4)));
typedef unsigned long long u64;

constexpr int kB  = 512;   // batch
constexpr int kT  = 512;   // seq len
constexpr int kI  = 128;   // input dim
constexpr int kH  = 512;   // hidden
constexpr int kNG = 2048;  // 4*H
constexpr int kO  = 128;   // output dim

// Padded K-stride (f16) for resident W in LDS. Byte stride 1300 -> 16B-group
// bank start = (5*lc + 4*lj) % 32, distinct for lc=0..15 => conflict-free b128
// (verified R5: SQ_LDS_BANK_CONFLICT 1.69e8 -> 0).
constexpr int LDK = 650;

__device__ __forceinline__ float fsig(float v)  { return 1.0f / (1.0f + __expf(-v)); }
__device__ __forceinline__ float ftanh(float v) { return 1.0f - 2.0f / (1.0f + __expf(2.0f * v)); }

union h8u { half8 h; u64 u[2]; };
union f16u { f16 f; unsigned short s; };

// 256 WGs x 256 threads (1 WG/CU, cooperative for co-residency + 2 one-time grid syncs).
// WG: bg = blockIdx&7 (64 batch rows), ng = blockIdx>>3 (h-slice of 16 cols).
// Per-step sync: 32-WG group barrier, ZERO fences. h data moves through
// relaxed AGENT-scope atomics (sc1: write-through-to/read-at IF$ coherence
// point) -- per-access coherence instead of bulk L2 flush/invalidate, which
// R4/R5 showed costs ~15 us/step. Visibility of these primitives was proven
// by R5's working gen-flag protocol (same relaxed-agent store/load).
__global__ __launch_bounds__(256, 1) void lstm_fused(
    const float* __restrict__ x,  const float* __restrict__ Wx,
    const float* __restrict__ Wh, const float* __restrict__ bias,
    const float* __restrict__ Wp, const float* __restrict__ bp,
    float* __restrict__ out, float* __restrict__ ws)
{
  cg::grid_group grid = cg::this_grid();

  // Resident weight slice, fp16: [col 0..63][k 0..639], padded stride LDK.
  __shared__ __align__(16) f16 w_lds[64 * LDK];

  const int tid = threadIdx.x;
  const int wg  = blockIdx.x;
  const int bg  = wg & 7;
  const int ng  = wg >> 3;
  const int b0  = bg * 64;
  const int wv  = tid >> 6;     // wave 0..3
  const int l   = tid & 63;
  const int lc  = l & 15;       // fragment row/col
  const int lj  = l >> 4;       // k-group 0..3

  f16* h16a = (f16*)ws;                 // [512][512] fp16
  f16* h16b = h16a + kB * kH;
  unsigned* bar = (unsigned*)(h16b + kB * kH);  // 8 groups: cnt @bg*64, gen @bg*64+32

  // ---- init: zero h0 and barrier area (ws poisoned; re-init every call) ----
  {
    int gtid = wg * 256 + tid;                 // 65536 threads
    unsigned* p = (unsigned*)h16a;             // 131072 u32 = 512 KB
    p[gtid * 2] = 0u; p[gtid * 2 + 1] = 0u;
    if (gtid < 512) bar[gtid] = 0u;
  }

  // ---- one-time: stage W slice -> LDS fp16 ----
  for (int idx = tid; idx < 64 * 640; idx += 256) {
    int c = idx & 63;
    int k = idx >> 6;
    int gcol = (c >> 4) * 512 + ng * 16 + (c & 15);
    float v = (k < 512) ? Wh[(long)k * kNG + gcol]
                        : Wx[(long)(k - 512) * kNG + gcol];
    w_lds[c * LDK + k] = (f16)v;
  }
  float bb[4];
  #pragma unroll
  for (int g = 0; g < 4; ++g) bb[g] = bias[g * 512 + ng * 16 + lc];

  float ce[4] = {0.f, 0.f, 0.f, 0.f};
  const int arow = b0 + wv * 16 + lc;
  const f16* wbase = w_lds + lc * LDK + lj * 8;
  const float* xrow = x + (long)arow * (kT * kI) + lj * 8;

  // grid.sync: release(wbl2) pushes the h zeros + bar zeros to IF$/HBM, so
  // subsequent sc1 (IF$-point) accesses observe them; also w_lds staged.
  grid.sync();

  unsigned* bcnt = bar + bg * 64;
  unsigned* bgen = bar + bg * 64 + 32;

  // preload x for t=0 (later steps prefetched before the barrier)
  float4v xa[4], xb[4];
  #pragma unroll
  for (int q = 0; q < 4; ++q) {
    xa[q] = *(const float4v*)(xrow + q * 32);
    xb[q] = *(const float4v*)(xrow + q * 32 + 4);
  }

  for (int t = 0; t < kT; ++t) {
    const f16* hc = (t & 1) ? h16b : h16a;
    f16*       hn = (t & 1) ? h16a : h16b;

    // h loads: relaxed agent atomics (sc1 -> read at IF$, always current).
    // u64 row stride = 128; lane base = arow*128 + lj*2; frag p at +p*8.
    const u64* hp64 = (const u64*)hc + (long)arow * 128 + lj * 2;
    h8u ah[16];
    #pragma unroll
    for (int p = 0; p < 16; ++p) {
      ah[p].u[0] = __hip_atomic_load(hp64 + p * 8,     __ATOMIC_RELAXED, __HIP_MEMORY_SCOPE_AGENT);
      ah[p].u[1] = __hip_atomic_load(hp64 + p * 8 + 1, __ATOMIC_RELAXED, __HIP_MEMORY_SCOPE_AGENT);
    }

    float4v acc[4];
    #pragma unroll
    for (int g = 0; g < 4; ++g) acc[g] = float4v{bb[g], bb[g], bb[g], bb[g]};

    // h @ Wh : 16 k-steps of 32, B from LDS (conflict-free layout)
    #pragma unroll
    for (int ks = 0; ks < 16; ++ks) {
      #pragma unroll
      for (int g = 0; g < 4; ++g) {
        half8 bf = *(const half8*)(wbase + g * 16 * LDK + ks * 32);
        acc[g] = __builtin_amdgcn_mfma_f32_16x16x32_f16(ah[ks].h, bf, acc[g], 0, 0, 0);
      }
    }
    // x_t @ Wx : 4 k-steps
    #pragma unroll
    for (int q = 0; q < 4; ++q) {
      half8 a;
      #pragma unroll
      for (int e = 0; e < 4; ++e) { a[e] = (f16)xa[q][e]; a[e + 4] = (f16)xb[q][e]; }
      #pragma unroll
      for (int g = 0; g < 4; ++g) {
        half8 bf = *(const half8*)(wbase + g * 16 * LDK + 512 + q * 32);
        acc[g] = __builtin_amdgcn_mfma_f32_16x16x32_f16(a, bf, acc[g], 0, 0, 0);
      }
    }

    // prefetch x for t+1 (read-only; overlaps gate update + barrier)
    if (t + 1 < kT) {
      const float* xn = xrow + (long)(t + 1) * kI;
      #pragma unroll
      for (int q = 0; q < 4; ++q) {
        xa[q] = *(const float4v*)(xn + q * 32);
        xb[q] = *(const float4v*)(xn + q * 32 + 4);
      }
    }

    // gate update in registers; h stored via relaxed agent atomics
    // (global_store_short sc1: write-through to IF$, no L2 flush needed)
    #pragma unroll
    for (int e = 0; e < 4; ++e) {
      float gv = ftanh(acc[0][e]);
      float iv = fsig(acc[1][e]);
      float fv = fsig(acc[2][e]);
      float ov = fsig(acc[3][e]);
      float cn = gv * iv + ce[e] * fv;
      ce[e] = cn;
      f16u hv; hv.f = (f16)(ftanh(cn) * ov);
      unsigned short* dst = (unsigned short*)hn
          + (long)(b0 + wv * 16 + lj * 4 + e) * kH + ng * 16 + lc;
      __hip_atomic_store(dst, hv.s, __ATOMIC_RELAXED, __HIP_MEMORY_SCOPE_AGENT);
    }

    // ---- 32-WG group barrier, fence-free ----
    // __syncthreads: every wave drains vmcnt(0) before s_barrier, so all
    // sc1 h-stores of this WG have reached the IF$ coherence point before
    // tid0 arrives. All barrier atomics relaxed (sc1, at IF$): no cache
    // maintenance anywhere in the loop.
    __syncthreads();
    if (tid == 0) {
      unsigned old = __hip_atomic_fetch_add(bcnt, 1u, __ATOMIC_RELAXED, __HIP_MEMORY_SCOPE_AGENT);
      if (old == (unsigned)(t * 32 + 31)) {
        __hip_atomic_store(bgen, (unsigned)(t + 1), __ATOMIC_RELAXED, __HIP_MEMORY_SCOPE_AGENT);
      } else {
        while (__hip_atomic_load(bgen, __ATOMIC_RELAXED, __HIP_MEMORY_SCOPE_AGENT) < (unsigned)(t + 1)) { }
      }
    }
    __syncthreads();
  }

  grid.sync();   // all bg-groups done; acquire side invalidates stale caches

  // ---- projection + softmax: rows wg*2, wg*2+1 (final h in h16a) ----
  const f16* hf = h16a;
  float* hrow = (float*)w_lds;             // reuse LDS
  float* red  = (float*)w_lds + 2 * kH;
  for (int i = tid; i < 2 * kH; i += 256) {
    int r = i >> 9, k = i & 511;
    hrow[i] = (float)hf[(long)(wg * 2 + r) * kH + k];
  }
  __syncthreads();

  const int orow = tid >> 7;   // 0..1
  const int oc   = tid & 127;  // 0..127
  float p = bp[oc];
  #pragma unroll 8
  for (int k = 0; k < kH; ++k)
    p += hrow[orow * kH + k] * Wp[(long)k * kO + oc];

  red[tid] = p;
  __syncthreads();
  float m = -1e30f;
  for (int j = 0; j < 128; ++j) m = fmaxf(m, red[orow * 128 + j]);
  __syncthreads();
  float e = __expf(p - m);
  red[tid] = e;
  __syncthreads();
  float s = 0.f;
  for (int j = 0; j < 128; ++j) s += red[orow * 128 + j];
  out[(long)(wg * 2 + orow) * kO + oc] = e / s;
}

extern "C" void kernel_launch(void* const* d_in, const int* in_sizes, int n_in,
                              void* d_out, int out_size, void* d_ws, size_t ws_size,
                              hipStream_t stream) {
  const float* x  = (const float*)d_in[0];
  const float* Wx = (const float*)d_in[1];
  const float* Wh = (const float*)d_in[2];
  const float* b  = (const float*)d_in[3];
  const float* Wp = (const float*)d_in[4];
  const float* bp = (const float*)d_in[5];
  float* out = (float*)d_out;
  float* ws  = (float*)d_ws;

  void* args[] = { &x, &Wx, &Wh, &b, &Wp, &bp, &out, &ws };
  hipLaunchCooperativeKernel((void*)lstm_fused, dim3(256), dim3(256), args, 0, stream);
}

// Round 7
// 5557.507 us; speedup vs baseline: 1.9980x; 1.0465x over previous
//
#include <hip/hip_runtime.h>
#include <hip/hip_cooperative_groups.h>

namespace cg = cooperative_groups;

typedef _Float16 f16;
typedef _Float16 half8 __attribute__((ext_vector_type(8)));
typedef float float4v __attribute__((ext_vector_type(4)));
typedef unsigned long long u64;

constexpr int kB  = 512;   // batch
constexpr int kT  = 512;   // seq len
constexpr int kI  = 128;   // input dim
constexpr int kH  = 512;   // hidden
constexpr int kNG = 2048;  // 4*H
constexpr int kO  = 128;   // output dim

// Padded K-stride (f16) for resident W in LDS. Byte stride 1300 -> conflict-free
// b128 (verified R5: SQ_LDS_BANK_CONFLICT 1.69e8 -> 0).
constexpr int LDK = 650;

__device__ __forceinline__ float fsig(float v)  { return 1.0f / (1.0f + __expf(-v)); }
__device__ __forceinline__ float ftanh(float v) { return 1.0f - 2.0f / (1.0f + __expf(2.0f * v)); }

union h8u { half8 h; u64 u[2]; };
union f16u { f16 f; unsigned short s; };

// 256 WGs x 256 threads (1 WG/CU, cooperative for co-residency + 2 one-time grid syncs).
// WG: bg = blockIdx&7 (64 batch rows), ng = blockIdx>>3 (h-slice of 16 cols).
// h exchange: relaxed AGENT (sc1) stores/loads -- per-access IF$ coherence, no
// fences anywhere in the loop (R6-proven). Per-step sync: FLAG-ARRAY barrier --
// each WG stores gen to its own 128B-spaced slot (no same-line RMW: R6's 32
// serialized fetch_adds ~= 9us/step), wave 0 polls all 32 slots in parallel.
__global__ __launch_bounds__(256, 1) void lstm_fused(
    const float* __restrict__ x,  const float* __restrict__ Wx,
    const float* __restrict__ Wh, const float* __restrict__ bias,
    const float* __restrict__ Wp, const float* __restrict__ bp,
    float* __restrict__ out, float* __restrict__ ws)
{
  cg::grid_group grid = cg::this_grid();

  // Resident weight slice, fp16: [col 0..63][k 0..639], padded stride LDK.
  __shared__ __align__(16) f16 w_lds[64 * LDK];

  const int tid = threadIdx.x;
  const int wg  = blockIdx.x;
  const int bg  = wg & 7;
  const int ng  = wg >> 3;
  const int b0  = bg * 64;
  const int wv  = tid >> 6;     // wave 0..3
  const int l   = tid & 63;
  const int lc  = l & 15;       // fragment row/col
  const int lj  = l >> 4;       // k-group 0..3

  f16* h16a = (f16*)ws;                 // [512][512] fp16
  f16* h16b = h16a + kB * kH;
  // flag array: 8 groups x 32 slots x 32 u32 (128B spacing) = 32 KB
  unsigned* bar = (unsigned*)(h16b + kB * kH);

  // ---- init: zero h0 and flag area (ws poisoned; re-init every call) ----
  {
    int gtid = wg * 256 + tid;                 // 65536 threads
    unsigned* p = (unsigned*)h16a;             // 131072 u32 = 512 KB
    p[gtid * 2] = 0u; p[gtid * 2 + 1] = 0u;
    if (gtid < 8192) bar[gtid] = 0u;
  }

  // ---- one-time: stage W slice -> LDS fp16 ----
  for (int idx = tid; idx < 64 * 640; idx += 256) {
    int c = idx & 63;
    int k = idx >> 6;
    int gcol = (c >> 4) * 512 + ng * 16 + (c & 15);
    float v = (k < 512) ? Wh[(long)k * kNG + gcol]
                        : Wx[(long)(k - 512) * kNG + gcol];
    w_lds[c * LDK + k] = (f16)v;
  }
  float bb[4];
  #pragma unroll
  for (int g = 0; g < 4; ++g) bb[g] = bias[g * 512 + ng * 16 + lc];

  float ce[4] = {0.f, 0.f, 0.f, 0.f};
  const int arow = b0 + wv * 16 + lc;
  const f16* wbase = w_lds + lc * LDK + lj * 8;
  const float* xrow = x + (long)arow * (kT * kI) + lj * 8;

  // preload x(0) before the grid sync (hides L3 latency under sync)
  float4v xa[4], xb[4];
  #pragma unroll
  for (int q = 0; q < 4; ++q) {
    xa[q] = *(const float4v*)(xrow + q * 32);
    xb[q] = *(const float4v*)(xrow + q * 32 + 4);
  }

  // grid.sync: h zeros + flag zeros flushed to IF$ (release side), w_lds staged.
  grid.sync();

  unsigned* myslot = bar + (bg * 32 + ng) * 32;
  const unsigned* pollslot = bar + (bg * 32 + (l & 31)) * 32;

  // xacc(0) = bias + x(0)@Wx ; then prefetch x(1)
  float4v xacc[4];
  #pragma unroll
  for (int g = 0; g < 4; ++g) xacc[g] = float4v{bb[g], bb[g], bb[g], bb[g]};
  #pragma unroll
  for (int q = 0; q < 4; ++q) {
    half8 a;
    #pragma unroll
    for (int e = 0; e < 4; ++e) { a[e] = (f16)xa[q][e]; a[e + 4] = (f16)xb[q][e]; }
    #pragma unroll
    for (int g = 0; g < 4; ++g) {
      half8 bf = *(const half8*)(wbase + g * 16 * LDK + 512 + q * 32);
      xacc[g] = __builtin_amdgcn_mfma_f32_16x16x32_f16(a, bf, xacc[g], 0, 0, 0);
    }
  }
  #pragma unroll
  for (int q = 0; q < 4; ++q) {
    xa[q] = *(const float4v*)(xrow + kI + q * 32);
    xb[q] = *(const float4v*)(xrow + kI + q * 32 + 4);
  }

  for (int t = 0; t < kT; ++t) {
    const f16* hc = (t & 1) ? h16b : h16a;
    f16*       hn = (t & 1) ? h16a : h16b;

    // h loads: relaxed agent (sc1 -> read at IF$, always current)
    const u64* hp64 = (const u64*)hc + (long)arow * 128 + lj * 2;
    h8u ah[16];
    #pragma unroll
    for (int p = 0; p < 16; ++p) {
      ah[p].u[0] = __hip_atomic_load(hp64 + p * 8,     __ATOMIC_RELAXED, __HIP_MEMORY_SCOPE_AGENT);
      ah[p].u[1] = __hip_atomic_load(hp64 + p * 8 + 1, __ATOMIC_RELAXED, __HIP_MEMORY_SCOPE_AGENT);
    }

    // z = xacc(t) + h@Wh
    float4v acc[4];
    #pragma unroll
    for (int g = 0; g < 4; ++g) acc[g] = xacc[g];

    #pragma unroll
    for (int ks = 0; ks < 16; ++ks) {
      #pragma unroll
      for (int g = 0; g < 4; ++g) {
        half8 bf = *(const half8*)(wbase + g * 16 * LDK + ks * 32);
        acc[g] = __builtin_amdgcn_mfma_f32_16x16x32_f16(ah[ks].h, bf, acc[g], 0, 0, 0);
      }
    }

    // gate update in registers; h stored via relaxed agent atomics (sc1)
    #pragma unroll
    for (int e = 0; e < 4; ++e) {
      float gv = ftanh(acc[0][e]);
      float iv = fsig(acc[1][e]);
      float fv = fsig(acc[2][e]);
      float ov = fsig(acc[3][e]);
      float cn = gv * iv + ce[e] * fv;
      ce[e] = cn;
      f16u hv; hv.f = (f16)(ftanh(cn) * ov);
      unsigned short* dst = (unsigned short*)hn
          + (long)(b0 + wv * 16 + lj * 4 + e) * kH + ng * 16 + lc;
      __hip_atomic_store(dst, hv.s, __ATOMIC_RELAXED, __HIP_MEMORY_SCOPE_AGENT);
    }

    // ---- flag-array group barrier ----
    // __syncthreads: each wave drains vmcnt(0) before s_barrier => all of
    // this WG's sc1 h-stores are at the IF$ coherence point before tid0's
    // flag store is issued. Flag stores go to 32 distinct lines (parallel).
    __syncthreads();
    if (tid == 0)
      __hip_atomic_store(myslot, (unsigned)(t + 1), __ATOMIC_RELAXED, __HIP_MEMORY_SCOPE_AGENT);

    // wait shadow: xacc(t+1) = bias + x(t+1)@Wx (independent of h), then
    // prefetch x(t+2) registers. Hidden under the poll.
    if (t + 1 < kT) {
      #pragma unroll
      for (int g = 0; g < 4; ++g) xacc[g] = float4v{bb[g], bb[g], bb[g], bb[g]};
      #pragma unroll
      for (int q = 0; q < 4; ++q) {
        half8 a;
        #pragma unroll
        for (int e = 0; e < 4; ++e) { a[e] = (f16)xa[q][e]; a[e + 4] = (f16)xb[q][e]; }
        #pragma unroll
        for (int g = 0; g < 4; ++g) {
          half8 bf = *(const half8*)(wbase + g * 16 * LDK + 512 + q * 32);
          xacc[g] = __builtin_amdgcn_mfma_f32_16x16x32_f16(a, bf, xacc[g], 0, 0, 0);
        }
      }
      if (t + 2 < kT) {
        const float* xn = xrow + (long)(t + 2) * kI;
        #pragma unroll
        for (int q = 0; q < 4; ++q) {
          xa[q] = *(const float4v*)(xn + q * 32);
          xb[q] = *(const float4v*)(xn + q * 32 + 4);
        }
      }
    }

    // wave-parallel poll: lane i watches slot (i&31); exit when all >= t+1
    if (wv == 0) {
      unsigned v;
      do {
        v = __hip_atomic_load(pollslot, __ATOMIC_RELAXED, __HIP_MEMORY_SCOPE_AGENT);
      } while (__all((int)(v >= (unsigned)(t + 1))) == 0);
    }
    __syncthreads();
  }

  grid.sync();   // all bg-groups done; acquire side invalidates stale caches

  // ---- projection + softmax: rows wg*2, wg*2+1 (final h in h16a) ----
  const f16* hf = h16a;
  float* hrow = (float*)w_lds;             // reuse LDS
  float* red  = (float*)w_lds + 2 * kH;
  for (int i = tid; i < 2 * kH; i += 256) {
    int r = i >> 9, k = i & 511;
    hrow[i] = (float)hf[(long)(wg * 2 + r) * kH + k];
  }
  __syncthreads();

  const int orow = tid >> 7;   // 0..1
  const int oc   = tid & 127;  // 0..127
  float p = bp[oc];
  #pragma unroll 8
  for (int k = 0; k < kH; ++k)
    p += hrow[orow * kH + k] * Wp[(long)k * kO + oc];

  red[tid] = p;
  __syncthreads();
  float m = -1e30f;
  for (int j = 0; j < 128; ++j) m = fmaxf(m, red[orow * 128 + j]);
  __syncthreads();
  float e = __expf(p - m);
  red[tid] = e;
  __syncthreads();
  float s = 0.f;
  for (int j = 0; j < 128; ++j) s += red[orow * 128 + j];
  out[(long)(wg * 2 + orow) * kO + oc] = e / s;
}

extern "C" void kernel_launch(void* const* d_in, const int* in_sizes, int n_in,
                              void* d_out, int out_size, void* d_ws, size_t ws_size,
                              hipStream_t stream) {
  const float* x  = (const float*)d_in[0];
  const float* Wx = (const float*)d_in[1];
  const float* Wh = (const float*)d_in[2];
  const float* b  = (const float*)d_in[3];
  const float* Wp = (const float*)d_in[4];
  const float* bp = (const float*)d_in[5];
  float* out = (float*)d_out;
  float* ws  = (float*)d_ws;

  void* args[] = { &x, &Wx, &Wh, &b, &Wp, &bp, &out, &ws };
  hipLaunchCooperativeKernel((void*)lstm_fused, dim3(256), dim3(256), args, 0, stream);
}